// Round 4
// baseline (335.613 us; speedup 1.0000x reference)
//
#include <hip/hip_runtime.h>
#include <hip/hip_bf16.h>

typedef unsigned short u16;
typedef unsigned int u32;
typedef __attribute__((ext_vector_type(8))) short bf16x8;
typedef __attribute__((ext_vector_type(4))) float f32x4;

#define MFMA(a, b, c) __builtin_amdgcn_mfma_f32_16x16x32_bf16(a, b, c, 0, 0, 0)

__device__ __forceinline__ u16 f2b(float f) {
    u32 x = __float_as_uint(f);
    return (u16)((x + 0x7fffu + ((x >> 16) & 1u)) >> 16);  // RNE, no NaN in data
}
__device__ __forceinline__ bf16x8 ldb8(const u16* p) {
    return *reinterpret_cast<const bf16x8*>(p);
}
__device__ __forceinline__ int cvt_pk(float lo, float hi) {
    int r;
    asm("v_cvt_pk_bf16_f32 %0, %1, %2" : "=v"(r) : "v"(lo), "v"(hi));
    return r;
}

// ---- convert weights to bf16 (w_qkv 384x256, w_out 256x128, same layouts) ----
__global__ void k_convw(const float* wq, const float* wo, u16* wqb, u16* wob) {
    int i4 = (blockIdx.x * 256 + threadIdx.x) * 4;
    const float* s;
    u16* d;
    if (i4 < 384 * 256) { s = wq + i4; d = wqb + i4; }
    else { int j = i4 - 384 * 256; s = wo + j; d = wob + j; }
    float4 v = *(const float4*)s;
    u16 o[4] = {f2b(v.x), f2b(v.y), f2b(v.z), f2b(v.w)};
    *(uint2*)d = *(uint2*)o;
}

// ---- generic 32x32-tiled transpose fp32[R][C] -> bf16[C][R], optional per-row scale ----
__global__ void k_trans(const float* __restrict__ src, u16* __restrict__ dst,
                        const float* __restrict__ scale,
                        int R, int C, int H, long sbB, long shB, int scb, int sch) {
    __shared__ float ld[32][33];
    int p = blockIdx.z;
    int b = p / H, h = p - b * H;
    const float* s = src + (long)b * sbB + (long)h * shB;
    u16* d = dst + (long)p * (long)R * (long)C;
    const float* sc = scale ? (scale + b * scb + h * sch) : nullptr;
    int c0 = blockIdx.x * 32, r0 = blockIdx.y * 32;
    int tx = threadIdx.x, ty = threadIdx.y;
#pragma unroll
    for (int i = 0; i < 4; i++) {
        int r = r0 + ty + 8 * i;
        float f = s[(long)r * C + c0 + tx];
        if (sc) f *= sc[r];
        ld[ty + 8 * i][tx] = f;
    }
    __syncthreads();
#pragma unroll
    for (int i = 0; i < 4; i++) {
        int c = c0 + ty + 8 * i;
        d[(long)c * R + r0 + tx] = f2b(ld[tx][ty + 8 * i]);
    }
}

// ---- GEMM1: Wqkv(384x256) x X_t. q,k rows (o<256) -> qkv f32 [b][256][4096]
// ----        + per-row sum-of-squares via atomics; v rows -> vb bf16 directly.
__global__ __launch_bounds__(256) void k_gemm1(const u16* __restrict__ wqb,
                                               const u16* __restrict__ xt,
                                               float* __restrict__ qkv,
                                               u16* __restrict__ vb,
                                               float* __restrict__ sumsq) {
    int lane = threadIdx.x & 63;
    int wid = blockIdx.x * 4 + (threadIdx.x >> 6);   // 6144 waves
    int b = wid / 1536;
    int rem = wid - b * 1536;
    int ot = rem >> 6, ng = rem & 63;
    int o0 = ot * 16, n0 = ng * 64;
    int lr = lane & 15, lg = lane >> 4;
    const u16* A = wqb + (o0 + lr) * 256 + lg * 8;
    const u16* B = xt + ((long)b * 4096 + n0 + lr) * 256 + lg * 8;
    f32x4 z = {0.f, 0.f, 0.f, 0.f};
    f32x4 acc[4] = {z, z, z, z};
#pragma unroll
    for (int kk = 0; kk < 8; kk++) {
        bf16x8 af = ldb8(A + kk * 32);
#pragma unroll
        for (int c = 0; c < 4; c++) {
            bf16x8 bb = ldb8(B + c * 16 * 256 + kk * 32);
            acc[c] = MFMA(af, bb, acc[c]);
        }
    }
    if (o0 < 256) {
        float* out = qkv + (long)b * 1048576 + (long)(o0 + lg * 4) * 4096 + n0 + lr;
#pragma unroll
        for (int c = 0; c < 4; c++)
#pragma unroll
            for (int r = 0; r < 4; r++)
                out[r * 4096 + c * 16] = acc[c][r];
        // per-row sum of squares for this wave's 64-n slice
        float sr[4];
#pragma unroll
        for (int r = 0; r < 4; r++) {
            sr[r] = acc[0][r] * acc[0][r] + acc[1][r] * acc[1][r]
                  + acc[2][r] * acc[2][r] + acc[3][r] * acc[3][r];
#pragma unroll
            for (int off = 1; off < 16; off <<= 1) sr[r] += __shfl_xor(sr[r], off);
        }
        if (lr == 0) {
#pragma unroll
            for (int r = 0; r < 4; r++)
                atomicAdd(sumsq + b * 256 + o0 + lg * 4 + r, sr[r]);
        }
    } else {
        u16* out = vb + (long)b * 524288 + (long)(o0 - 256 + lg * 4) * 4096 + n0 + lr;
#pragma unroll
        for (int c = 0; c < 4; c++)
#pragma unroll
            for (int r = 0; r < 4; r++)
                out[r * 4096 + c * 16] = f2b(acc[c][r]);
    }
}

// ---- inv scales from sum-of-squares; folds 10*log2(e) into q rows ----
__global__ void k_inv(const float* __restrict__ sumsq, float* __restrict__ inv) {
    int row = blockIdx.x * 256 + threadIdx.x;   // 1024 rows
    int o = row & 255;
    float mult = (o < 128) ? 14.426950408889634f : 1.0f;
    inv[row] = mult / fmaxf(sqrtf(sumsq[row]), 1e-12f);
}

// ---- flash attention, in-register P; block = (bh, 64 i-rows), 8 waves =
// ---- 2 i-subtiles x 4 j-quarters, LDS partial combine. lsum via ones-MFMA.
__global__ __launch_bounds__(512, 8) void k_attn(const u16* __restrict__ qt,
                                                 const u16* __restrict__ kt,
                                                 const u16* __restrict__ vb,
                                                 u16* __restrict__ ot) {
    __shared__ f32x4 lacc[3][2][2][2][64];   // [js-1][isub][tau][t][lane]
    __shared__ float lls[3][2][2][64];       // [js-1][isub][tau][lane]
    int wv = threadIdx.x >> 6, lane = threadIdx.x & 63;
    int isub = wv & 1, js = wv >> 1;
    int bid = blockIdx.x;
    int swz = (bid & 7) * 128 + (bid >> 3);  // XCD swizzle, 1024 % 8 == 0
    int bh = swz >> 6, iblk = swz & 63;
    int lr = lane & 15, lg = lane >> 4;
    long base = (long)bh * 131072;           // 4096*32 elements per (b,h)
    int i0 = iblk * 64 + isub * 32;

    bf16x8 qa[2];
    qa[0] = ldb8(qt + base + (long)(i0 + lr) * 32 + lg * 8);
    qa[1] = ldb8(qt + base + (long)(i0 + 16 + lr) * 32 + lg * 8);

    union { u32 w[4]; bf16x8 v; } ones;
    ones.w[0] = ones.w[1] = ones.w[2] = ones.w[3] = 0x3F803F80u;  // bf16 1.0 x8

    f32x4 z = {0.f, 0.f, 0.f, 0.f};
    f32x4 acc[2][2] = {{z, z}, {z, z}};
    f32x4 accl[2] = {z, z};

    const u16* Kp = kt + base + (long)(js * 1024) * 32 + lr * 32 + lg * 8;
    const u16* Vp = vb + base + (long)lr * 4096 + js * 1024 + lg * 8;

    for (int j0 = 0; j0 < 1024; j0 += 32) {
        bf16x8 kb0 = ldb8(Kp + j0 * 32);
        bf16x8 kb1 = ldb8(Kp + j0 * 32 + 512);
        bf16x8 va0 = ldb8(Vp + j0);
        bf16x8 va1 = ldb8(Vp + 65536 + j0);
#pragma unroll
        for (int tau = 0; tau < 2; tau++) {
            // Swapped QK^T: lane holds S^T[j = 4*lg + r][i = lr] per 16-j tile.
            f32x4 s0 = MFMA(kb0, qa[tau], z);
            f32x4 s1 = MFMA(kb1, qa[tau], z);
            float p0[4], p1[4];
#pragma unroll
            for (int r = 0; r < 4; r++) {
                p0[r] = __builtin_amdgcn_exp2f(s0[r]);
                p1[r] = __builtin_amdgcn_exp2f(s1[r]);
            }
            // Pack pairs and redistribute: lane lg holds m(2lg),m(2lg+1),
            // m(8+2lg),m(8+2lg+1); B-frag needs m(4lg+e). swap32 then swap16.
            int a0 = cvt_pk(p0[0], p0[1]);
            int a1 = cvt_pk(p0[2], p0[3]);
            int b0 = cvt_pk(p1[0], p1[1]);
            int b1 = cvt_pk(p1[2], p1[3]);
            {
                auto r0_ = __builtin_amdgcn_permlane32_swap(a0, b0, false, false);
                a0 = r0_[0]; b0 = r0_[1];
                auto r1_ = __builtin_amdgcn_permlane32_swap(a1, b1, false, false);
                a1 = r1_[0]; b1 = r1_[1];
                auto r2_ = __builtin_amdgcn_permlane16_swap(a0, b0, false, false);
                a0 = r2_[0]; b0 = r2_[1];
                auto r3_ = __builtin_amdgcn_permlane16_swap(a1, b1, false, false);
                a1 = r3_[0]; b1 = r3_[1];
            }
            union { int w[4]; bf16x8 v; } pu;
            pu.w[0] = a0; pu.w[1] = a1; pu.w[2] = b0; pu.w[3] = b1;
            acc[tau][0] = MFMA(va0, pu.v, acc[tau][0]);
            acc[tau][1] = MFMA(va1, pu.v, acc[tau][1]);
            accl[tau] = MFMA(ones.v, pu.v, accl[tau]);  // row-sums: K-reduce over j
        }
    }

    if (js > 0) {
#pragma unroll
        for (int tau = 0; tau < 2; tau++) {
            lacc[js - 1][isub][tau][0][lane] = acc[tau][0];
            lacc[js - 1][isub][tau][1][lane] = acc[tau][1];
            lls[js - 1][isub][tau][lane] = accl[tau][0];
        }
    }
    __syncthreads();
    if (js == 0) {
        int b = bh >> 2, h = bh & 3;
#pragma unroll
        for (int tau = 0; tau < 2; tau++) {
            float l = accl[tau][0];
#pragma unroll
            for (int jj = 0; jj < 3; jj++) l += lls[jj][isub][tau][lane];
            float linv = 1.0f / l;
            u16* op = ot + ((long)(b * 4096 + i0 + tau * 16 + lr)) * 128 + h * 32;
#pragma unroll
            for (int t = 0; t < 2; t++) {
                f32x4 o = acc[tau][t];
#pragma unroll
                for (int jj = 0; jj < 3; jj++) o += lacc[jj][isub][tau][t][lane];
#pragma unroll
                for (int s = 0; s < 2; s++) {
                    int w = cvt_pk(o[2 * s] * linv, o[2 * s + 1] * linv);
                    *(int*)(op + 16 * t + 4 * lg + 2 * s) = w;
                }
            }
        }
    }
}

// ---- GEMM2: y[b][256][4096] f32 = Wout(256x128) x O_t + b_out ----
__global__ __launch_bounds__(256) void k_gemm2(const u16* __restrict__ wob,
                                               const u16* __restrict__ ot,
                                               const float* __restrict__ bout,
                                               float* __restrict__ y) {
    int lane = threadIdx.x & 63;
    int wid = blockIdx.x * 4 + (threadIdx.x >> 6);   // 4096 waves
    int b = wid >> 10;
    int rem = wid & 1023;
    int otl = rem >> 6, ng = rem & 63;
    int o0 = otl * 16, n0 = ng * 64;
    int lr = lane & 15, lg = lane >> 4;
    const u16* A = wob + (o0 + lr) * 128 + lg * 8;
    const u16* B = ot + ((long)b * 4096 + n0 + lr) * 128 + lg * 8;
    f32x4 z = {0.f, 0.f, 0.f, 0.f};
    f32x4 acc[4] = {z, z, z, z};
#pragma unroll
    for (int kk = 0; kk < 4; kk++) {
        bf16x8 af = ldb8(A + kk * 32);
#pragma unroll
        for (int c = 0; c < 4; c++) {
            bf16x8 bb = ldb8(B + c * 16 * 128 + kk * 32);
            acc[c] = MFMA(af, bb, acc[c]);
        }
    }
    float bo[4];
#pragma unroll
    for (int r = 0; r < 4; r++) bo[r] = bout[o0 + lg * 4 + r];
    float* out = y + (long)b * 1048576 + (long)(o0 + lg * 4) * 4096 + n0 + lr;
#pragma unroll
    for (int c = 0; c < 4; c++)
#pragma unroll
        for (int r = 0; r < 4; r++)
            out[r * 4096 + c * 16] = acc[c][r] + bo[r];
}

extern "C" void kernel_launch(void* const* d_in, const int* in_sizes, int n_in,
                              void* d_out, int out_size, void* d_ws, size_t ws_size,
                              hipStream_t stream) {
    const float* x    = (const float*)d_in[0];
    const float* wqkv = (const float*)d_in[1];
    const float* wout = (const float*)d_in[2];
    const float* bout = (const float*)d_in[3];
    float* y = (float*)d_out;
    char* ws = (char*)d_ws;

    u16*   wqb   = (u16*)(ws);                 //   196,608 B
    u16*   wob   = (u16*)(ws + 196608);        //    65,536
    u16*   xt    = (u16*)(ws + 262144);        // 8,388,608
    float* qkv   = (float*)(ws + 8650752);     // 16,777,216  (q,k only)
    float* inv   = (float*)(ws + 25427968);    //     4,096
    float* sumsq = (float*)(ws + 25432064);    //     4,096
    u16*   qt    = (u16*)(ws + 25436160);      // 4,194,304
    u16*   kt    = (u16*)(ws + 29630464);      // 4,194,304
    u16*   vb    = (u16*)(ws + 33824768);      // 4,194,304
    u16*   ot    = (u16*)(ws + 38019072);      // 4,194,304  -> total 42,213,376 B

    hipMemsetAsync(sumsq, 0, 4096, stream);
    k_convw<<<128, 256, 0, stream>>>(wqkv, wout, wqb, wob);
    k_trans<<<dim3(128, 8, 4), dim3(32, 8), 0, stream>>>(
        x, xt, nullptr, 256, 4096, 1, 1048576L, 0L, 0, 0);
    k_gemm1<<<1536, 256, 0, stream>>>(wqb, xt, qkv, vb, sumsq);
    k_inv<<<4, 256, 0, stream>>>(sumsq, inv);
    k_trans<<<dim3(128, 1, 16), dim3(32, 8), 0, stream>>>(
        qkv, qt, inv, 32, 4096, 4, 1048576L, 131072L, 256, 32);
    k_trans<<<dim3(128, 1, 16), dim3(32, 8), 0, stream>>>(
        qkv + 524288, kt, inv + 128, 32, 4096, 4, 1048576L, 131072L, 256, 32);
    k_attn<<<1024, 512, 0, stream>>>(qt, kt, vb, ot);
    k_gemm2<<<1024, 256, 0, stream>>>(wob, ot, bout, y);
}

// Round 5
// 224.595 us; speedup vs baseline: 1.4943x; 1.4943x over previous
//
#include <hip/hip_runtime.h>
#include <hip/hip_bf16.h>

typedef unsigned short u16;
typedef unsigned int u32;
typedef __attribute__((ext_vector_type(8))) short bf16x8;
typedef __attribute__((ext_vector_type(4))) float f32x4;

#define MFMA(a, b, c) __builtin_amdgcn_mfma_f32_16x16x32_bf16(a, b, c, 0, 0, 0)

__device__ __forceinline__ u16 f2b(float f) {
    u32 x = __float_as_uint(f);
    return (u16)((x + 0x7fffu + ((x >> 16) & 1u)) >> 16);  // RNE, no NaN in data
}
__device__ __forceinline__ bf16x8 ldb8(const u16* p) {
    return *reinterpret_cast<const bf16x8*>(p);
}
__device__ __forceinline__ int cvt_pk(float lo, float hi) {
    int r;
    asm("v_cvt_pk_bf16_f32 %0, %1, %2" : "=v"(r) : "v"(lo), "v"(hi));
    return r;
}

// ---- convert weights to bf16 (w_qkv 384x256, w_out 256x128, same layouts) ----
__global__ void k_convw(const float* wq, const float* wo, u16* wqb, u16* wob) {
    int i4 = (blockIdx.x * 256 + threadIdx.x) * 4;
    const float* s;
    u16* d;
    if (i4 < 384 * 256) { s = wq + i4; d = wqb + i4; }
    else { int j = i4 - 384 * 256; s = wo + j; d = wob + j; }
    float4 v = *(const float4*)s;
    u16 o[4] = {f2b(v.x), f2b(v.y), f2b(v.z), f2b(v.w)};
    *(uint2*)d = *(uint2*)o;
}

// ---- generic 32x32-tiled transpose fp32[R][C] -> bf16[C][R], optional per-row scale ----
__global__ void k_trans(const float* __restrict__ src, u16* __restrict__ dst,
                        const float* __restrict__ scale,
                        int R, int C, int H, long sbB, long shB, int scb, int sch) {
    __shared__ float ld[32][33];
    int p = blockIdx.z;
    int b = p / H, h = p - b * H;
    const float* s = src + (long)b * sbB + (long)h * shB;
    u16* d = dst + (long)p * (long)R * (long)C;
    const float* sc = scale ? (scale + b * scb + h * sch) : nullptr;
    int c0 = blockIdx.x * 32, r0 = blockIdx.y * 32;
    int tx = threadIdx.x, ty = threadIdx.y;
#pragma unroll
    for (int i = 0; i < 4; i++) {
        int r = r0 + ty + 8 * i;
        float f = s[(long)r * C + c0 + tx];
        if (sc) f *= sc[r];
        ld[ty + 8 * i][tx] = f;
    }
    __syncthreads();
#pragma unroll
    for (int i = 0; i < 4; i++) {
        int c = c0 + ty + 8 * i;
        d[(long)c * R + r0 + tx] = f2b(ld[tx][ty + 8 * i]);
    }
}

// ---- GEMM1: Wqkv(384x256) x X_t.
// ----   o<128  (q): f32 -> qkvq [b][128][4096] + sumsq atomics
// ----   o<256  (k): sumsq atomics + bf16 kt [bh][4096][32] (LDS transpose repack)
// ----   o>=256 (v): bf16 vb [b][128][4096] directly
__global__ __launch_bounds__(256) void k_gemm1(const u16* __restrict__ wqb,
                                               const u16* __restrict__ xt,
                                               float* __restrict__ qkvq,
                                               u16* __restrict__ kt,
                                               u16* __restrict__ vb,
                                               float* __restrict__ sumsq) {
    __shared__ __align__(16) u16 tile[4][64][24];   // per-wave kt repack, pitch 24
    int lane = threadIdx.x & 63;
    int wvid = threadIdx.x >> 6;
    int wid = blockIdx.x * 4 + wvid;                // 6144 waves
    int b = wid / 1536;
    int rem = wid - b * 1536;
    int ot = rem >> 6, ng = rem & 63;
    int o0 = ot * 16, n0 = ng * 64;
    int lr = lane & 15, lg = lane >> 4;
    const u16* A = wqb + (o0 + lr) * 256 + lg * 8;
    const u16* B = xt + ((long)b * 4096 + n0 + lr) * 256 + lg * 8;
    f32x4 z = {0.f, 0.f, 0.f, 0.f};
    f32x4 acc[4] = {z, z, z, z};
#pragma unroll
    for (int kk = 0; kk < 8; kk++) {
        bf16x8 af = ldb8(A + kk * 32);
#pragma unroll
        for (int c = 0; c < 4; c++) {
            bf16x8 bb = ldb8(B + c * 16 * 256 + kk * 32);
            acc[c] = MFMA(af, bb, acc[c]);
        }
    }
    if (o0 < 256) {
        // per-row sum of squares (q and k rows)
        float sr[4];
#pragma unroll
        for (int r = 0; r < 4; r++) {
            sr[r] = acc[0][r] * acc[0][r] + acc[1][r] * acc[1][r]
                  + acc[2][r] * acc[2][r] + acc[3][r] * acc[3][r];
#pragma unroll
            for (int off = 1; off < 16; off <<= 1) sr[r] += __shfl_xor(sr[r], off);
        }
        if (lr == 0) {
#pragma unroll
            for (int r = 0; r < 4; r++)
                atomicAdd(sumsq + b * 256 + o0 + lg * 4 + r, sr[r]);
        }
    }
    if (o0 < 128) {
        float* out = qkvq + (long)b * 524288 + (long)(o0 + lg * 4) * 4096 + n0 + lr;
#pragma unroll
        for (int c = 0; c < 4; c++)
#pragma unroll
            for (int r = 0; r < 4; r++)
                out[r * 4096 + c * 16] = acc[c][r];
    } else if (o0 < 256) {
        // k -> kt[bh][n][32] bf16, transposed via per-wave LDS tile (no barrier:
        // same-wave write->read, compiler inserts lgkmcnt)
        int od0 = o0 - 128;                  // 0..127, multiple of 16
        int h = od0 >> 5;
#pragma unroll
        for (int c = 0; c < 4; c++)
#pragma unroll
            for (int r = 0; r < 4; r++)
                tile[wvid][c * 16 + lr][lg * 4 + r] = f2b(acc[c][r]);
        bf16x8 t0 = *(const bf16x8*)&tile[wvid][lane][0];
        bf16x8 t1 = *(const bf16x8*)&tile[wvid][lane][8];
        u16* dst = kt + ((long)(b * 4 + h)) * 131072 + (long)(n0 + lane) * 32 + (od0 & 16);
        *(bf16x8*)dst = t0;
        *(bf16x8*)(dst + 8) = t1;
    } else {
        u16* out = vb + (long)b * 524288 + (long)(o0 - 256 + lg * 4) * 4096 + n0 + lr;
#pragma unroll
        for (int c = 0; c < 4; c++)
#pragma unroll
            for (int r = 0; r < 4; r++)
                out[r * 4096 + c * 16] = f2b(acc[c][r]);
    }
}

// ---- combined scale for q: 10*log2(e) / (||q_row|| * ||k_row||) ----
__global__ void k_inv(const float* __restrict__ sumsq, float* __restrict__ inv) {
    int i = blockIdx.x * 256 + threadIdx.x;   // 512 rows: [b][128]
    int b = i >> 7, o = i & 127;
    float nq = fmaxf(sqrtf(sumsq[b * 256 + o]), 1e-12f);
    float nk = fmaxf(sqrtf(sumsq[b * 256 + 128 + o]), 1e-12f);
    inv[i] = 14.426950408889634f / (nq * nk);
}

// ---- flash attention, in-register P; block = (bh, 64 i-rows), 8 waves =
// ---- 2 i-subtiles x 4 j-quarters, LDS partial combine. lsum via ones-MFMA.
__global__ __launch_bounds__(512, 4) void k_attn(const u16* __restrict__ qt,
                                                 const u16* __restrict__ kt,
                                                 const u16* __restrict__ vb,
                                                 u16* __restrict__ ot) {
    __shared__ f32x4 lacc[3][2][2][2][64];   // [js-1][isub][tau][t][lane]
    __shared__ float lls[3][2][2][64];       // [js-1][isub][tau][lane]
    int wv = threadIdx.x >> 6, lane = threadIdx.x & 63;
    int isub = wv & 1, js = wv >> 1;
    int bid = blockIdx.x;
    int swz = (bid & 7) * 128 + (bid >> 3);  // XCD swizzle, 1024 % 8 == 0
    int bh = swz >> 6, iblk = swz & 63;
    int lr = lane & 15, lg = lane >> 4;
    long base = (long)bh * 131072;           // 4096*32 elements per (b,h)
    int i0 = iblk * 64 + isub * 32;

    bf16x8 qa[2];
    qa[0] = ldb8(qt + base + (long)(i0 + lr) * 32 + lg * 8);
    qa[1] = ldb8(qt + base + (long)(i0 + 16 + lr) * 32 + lg * 8);

    union { u32 w[4]; bf16x8 v; } ones;
    ones.w[0] = ones.w[1] = ones.w[2] = ones.w[3] = 0x3F803F80u;  // bf16 1.0 x8

    f32x4 z = {0.f, 0.f, 0.f, 0.f};
    f32x4 acc[2][2] = {{z, z}, {z, z}};
    f32x4 accl[2] = {z, z};

    const u16* Kp = kt + base + (long)(js * 1024) * 32 + lr * 32 + lg * 8;
    const u16* Vp = vb + base + (long)lr * 4096 + js * 1024 + lg * 8;

    for (int j0 = 0; j0 < 1024; j0 += 32) {
        bf16x8 kb0 = ldb8(Kp + j0 * 32);
        bf16x8 kb1 = ldb8(Kp + j0 * 32 + 512);
        bf16x8 va0 = ldb8(Vp + j0);
        bf16x8 va1 = ldb8(Vp + 65536 + j0);
#pragma unroll
        for (int tau = 0; tau < 2; tau++) {
            // Swapped QK^T: lane holds S^T[j = 4*lg + r][i = lr] per 16-j tile.
            f32x4 s0 = MFMA(kb0, qa[tau], z);
            f32x4 s1 = MFMA(kb1, qa[tau], z);
            float p0[4], p1[4];
#pragma unroll
            for (int r = 0; r < 4; r++) {
                p0[r] = __builtin_amdgcn_exp2f(s0[r]);
                p1[r] = __builtin_amdgcn_exp2f(s1[r]);
            }
            // Pack pairs and redistribute: lane lg holds m(2lg),m(2lg+1),
            // m(8+2lg),m(8+2lg+1); B-frag needs m(4lg+e). swap32 then swap16.
            int a0 = cvt_pk(p0[0], p0[1]);
            int a1 = cvt_pk(p0[2], p0[3]);
            int b0 = cvt_pk(p1[0], p1[1]);
            int b1 = cvt_pk(p1[2], p1[3]);
            {
                auto r0_ = __builtin_amdgcn_permlane32_swap(a0, b0, false, false);
                a0 = r0_[0]; b0 = r0_[1];
                auto r1_ = __builtin_amdgcn_permlane32_swap(a1, b1, false, false);
                a1 = r1_[0]; b1 = r1_[1];
                auto r2_ = __builtin_amdgcn_permlane16_swap(a0, b0, false, false);
                a0 = r2_[0]; b0 = r2_[1];
                auto r3_ = __builtin_amdgcn_permlane16_swap(a1, b1, false, false);
                a1 = r3_[0]; b1 = r3_[1];
            }
            union { int w[4]; bf16x8 v; } pu;
            pu.w[0] = a0; pu.w[1] = a1; pu.w[2] = b0; pu.w[3] = b1;
            acc[tau][0] = MFMA(va0, pu.v, acc[tau][0]);
            acc[tau][1] = MFMA(va1, pu.v, acc[tau][1]);
            accl[tau] = MFMA(ones.v, pu.v, accl[tau]);  // row-sums: K-reduce over j
        }
    }

    if (js > 0) {
#pragma unroll
        for (int tau = 0; tau < 2; tau++) {
            lacc[js - 1][isub][tau][0][lane] = acc[tau][0];
            lacc[js - 1][isub][tau][1][lane] = acc[tau][1];
            lls[js - 1][isub][tau][lane] = accl[tau][0];
        }
    }
    __syncthreads();
    if (js == 0) {
        int b = bh >> 2, h = bh & 3;
#pragma unroll
        for (int tau = 0; tau < 2; tau++) {
            float l = accl[tau][0];
#pragma unroll
            for (int jj = 0; jj < 3; jj++) l += lls[jj][isub][tau][lane];
            float linv = 1.0f / l;
            u16* op = ot + ((long)(b * 4096 + i0 + tau * 16 + lr)) * 128 + h * 32;
#pragma unroll
            for (int t = 0; t < 2; t++) {
                f32x4 o = acc[tau][t];
#pragma unroll
                for (int jj = 0; jj < 3; jj++) o += lacc[jj][isub][tau][t][lane];
#pragma unroll
                for (int s = 0; s < 2; s++) {
                    int w = cvt_pk(o[2 * s] * linv, o[2 * s + 1] * linv);
                    *(int*)(op + 16 * t + 4 * lg + 2 * s) = w;
                }
            }
        }
    }
}

// ---- GEMM2: y[b][256][4096] f32 = Wout(256x128) x O_t + b_out ----
__global__ __launch_bounds__(256) void k_gemm2(const u16* __restrict__ wob,
                                               const u16* __restrict__ ot,
                                               const float* __restrict__ bout,
                                               float* __restrict__ y) {
    int lane = threadIdx.x & 63;
    int wid = blockIdx.x * 4 + (threadIdx.x >> 6);   // 4096 waves
    int b = wid >> 10;
    int rem = wid & 1023;
    int otl = rem >> 6, ng = rem & 63;
    int o0 = otl * 16, n0 = ng * 64;
    int lr = lane & 15, lg = lane >> 4;
    const u16* A = wob + (o0 + lr) * 128 + lg * 8;
    const u16* B = ot + ((long)b * 4096 + n0 + lr) * 128 + lg * 8;
    f32x4 z = {0.f, 0.f, 0.f, 0.f};
    f32x4 acc[4] = {z, z, z, z};
#pragma unroll
    for (int kk = 0; kk < 4; kk++) {
        bf16x8 af = ldb8(A + kk * 32);
#pragma unroll
        for (int c = 0; c < 4; c++) {
            bf16x8 bb = ldb8(B + c * 16 * 128 + kk * 32);
            acc[c] = MFMA(af, bb, acc[c]);
        }
    }
    float bo[4];
#pragma unroll
    for (int r = 0; r < 4; r++) bo[r] = bout[o0 + lg * 4 + r];
    float* out = y + (long)b * 1048576 + (long)(o0 + lg * 4) * 4096 + n0 + lr;
#pragma unroll
    for (int c = 0; c < 4; c++)
#pragma unroll
        for (int r = 0; r < 4; r++)
            out[r * 4096 + c * 16] = acc[c][r] + bo[r];
}

extern "C" void kernel_launch(void* const* d_in, const int* in_sizes, int n_in,
                              void* d_out, int out_size, void* d_ws, size_t ws_size,
                              hipStream_t stream) {
    const float* x    = (const float*)d_in[0];
    const float* wqkv = (const float*)d_in[1];
    const float* wout = (const float*)d_in[2];
    const float* bout = (const float*)d_in[3];
    float* y = (float*)d_out;
    char* ws = (char*)d_ws;

    u16*   wqb   = (u16*)(ws);                 //   196,608 B
    u16*   wob   = (u16*)(ws + 196608);        //    65,536
    u16*   xt    = (u16*)(ws + 262144);        // 8,388,608
    float* qkvq  = (float*)(ws + 8650752);     // 8,388,608  (q only)
    float* inv   = (float*)(ws + 17039360);    //     2,048
    float* sumsq = (float*)(ws + 17041408);    //     4,096
    u16*   qt    = (u16*)(ws + 17045504);      // 4,194,304
    u16*   kt    = (u16*)(ws + 21239808);      // 4,194,304
    u16*   vb    = (u16*)(ws + 25434112);      // 4,194,304
    u16*   ot    = (u16*)(ws + 29628416);      // 4,194,304  -> total 33,822,720 B

    hipMemsetAsync(sumsq, 0, 4096, stream);
    k_convw<<<128, 256, 0, stream>>>(wqkv, wout, wqb, wob);
    k_trans<<<dim3(128, 8, 4), dim3(32, 8), 0, stream>>>(
        x, xt, nullptr, 256, 4096, 1, 1048576L, 0L, 0, 0);
    k_gemm1<<<1536, 256, 0, stream>>>(wqb, xt, qkvq, kt, vb, sumsq);
    k_inv<<<2, 256, 0, stream>>>(sumsq, inv);
    k_trans<<<dim3(128, 1, 16), dim3(32, 8), 0, stream>>>(
        qkvq, qt, inv, 32, 4096, 4, 524288L, 131072L, 128, 32);
    k_attn<<<1024, 512, 0, stream>>>(qt, kt, vb, ot);
    k_gemm2<<<1024, 256, 0, stream>>>(wob, ot, bout, y);
}

// Round 9
// 187.866 us; speedup vs baseline: 1.7864x; 1.1955x over previous
//
#include <hip/hip_runtime.h>
#include <hip/hip_bf16.h>

typedef unsigned short u16;
typedef unsigned int u32;
typedef __attribute__((ext_vector_type(8))) short bf16x8;
typedef __attribute__((ext_vector_type(4))) float f32x4;

#define MFMA(a, b, c) __builtin_amdgcn_mfma_f32_16x16x32_bf16(a, b, c, 0, 0, 0)

__device__ __forceinline__ u16 f2b(float f) {
    u32 x = __float_as_uint(f);
    return (u16)((x + 0x7fffu + ((x >> 16) & 1u)) >> 16);  // RNE, no NaN in data
}
__device__ __forceinline__ bf16x8 ldb8(const u16* p) {
    return *reinterpret_cast<const bf16x8*>(p);
}
__device__ __forceinline__ int cvt_pk(float lo, float hi) {
    int r;
    asm("v_cvt_pk_bf16_f32 %0, %1, %2" : "=v"(r) : "v"(lo), "v"(hi));
    return r;
}

// ---- convert weights to bf16 (w_qkv 384x256, w_out 256x128, same layouts) ----
__global__ void k_convw(const float* wq, const float* wo, u16* wqb, u16* wob) {
    int i4 = (blockIdx.x * 256 + threadIdx.x) * 4;
    const float* s;
    u16* d;
    if (i4 < 384 * 256) { s = wq + i4; d = wqb + i4; }
    else { int j = i4 - 384 * 256; s = wo + j; d = wob + j; }
    float4 v = *(const float4*)s;
    u16 o[4] = {f2b(v.x), f2b(v.y), f2b(v.z), f2b(v.w)};
    *(uint2*)d = *(uint2*)o;
}

// ---- generic 32x32-tiled transpose fp32[R][C] -> bf16[C][R], optional per-row scale ----
__global__ void k_trans(const float* __restrict__ src, u16* __restrict__ dst,
                        const float* __restrict__ scale,
                        int R, int C, int H, long sbB, long shB, int scb, int sch) {
    __shared__ float ld[32][33];
    int p = blockIdx.z;
    int b = p / H, h = p - b * H;
    const float* s = src + (long)b * sbB + (long)h * shB;
    u16* d = dst + (long)p * (long)R * (long)C;
    const float* sc = scale ? (scale + b * scb + h * sch) : nullptr;
    int c0 = blockIdx.x * 32, r0 = blockIdx.y * 32;
    int tx = threadIdx.x, ty = threadIdx.y;
#pragma unroll
    for (int i = 0; i < 4; i++) {
        int r = r0 + ty + 8 * i;
        float f = s[(long)r * C + c0 + tx];
        if (sc) f *= sc[r];
        ld[ty + 8 * i][tx] = f;
    }
    __syncthreads();
#pragma unroll
    for (int i = 0; i < 4; i++) {
        int c = c0 + ty + 8 * i;
        d[(long)c * R + r0 + tx] = f2b(ld[tx][ty + 8 * i]);
    }
}

// ---- GEMM1: Wqkv(384x256) x X_t.
// ----   o<128  (q): f32 -> qkvq [b][128][4096] + sumsq atomics
// ----   o<256  (k): sumsq atomics + bf16 kt [bh][4096][32] (LDS transpose repack)
// ----   o>=256 (v): bf16 vb [b][128][4096] directly
__global__ __launch_bounds__(256) void k_gemm1(const u16* __restrict__ wqb,
                                               const u16* __restrict__ xt,
                                               float* __restrict__ qkvq,
                                               u16* __restrict__ kt,
                                               u16* __restrict__ vb,
                                               float* __restrict__ sumsq) {
    __shared__ __align__(16) u16 tile[4][64][24];   // per-wave kt repack, pitch 24
    int lane = threadIdx.x & 63;
    int wvid = threadIdx.x >> 6;
    int wid = blockIdx.x * 4 + wvid;                // 6144 waves
    int b = wid / 1536;
    int rem = wid - b * 1536;
    int ot = rem >> 6, ng = rem & 63;
    int o0 = ot * 16, n0 = ng * 64;
    int lr = lane & 15, lg = lane >> 4;
    const u16* A = wqb + (o0 + lr) * 256 + lg * 8;
    const u16* B = xt + ((long)b * 4096 + n0 + lr) * 256 + lg * 8;
    f32x4 z = {0.f, 0.f, 0.f, 0.f};
    f32x4 acc[4] = {z, z, z, z};
#pragma unroll
    for (int kk = 0; kk < 8; kk++) {
        bf16x8 af = ldb8(A + kk * 32);
#pragma unroll
        for (int c = 0; c < 4; c++) {
            bf16x8 bb = ldb8(B + c * 16 * 256 + kk * 32);
            acc[c] = MFMA(af, bb, acc[c]);
        }
    }
    if (o0 < 256) {
        // per-row sum of squares (q and k rows)
        float sr[4];
#pragma unroll
        for (int r = 0; r < 4; r++) {
            sr[r] = acc[0][r] * acc[0][r] + acc[1][r] * acc[1][r]
                  + acc[2][r] * acc[2][r] + acc[3][r] * acc[3][r];
#pragma unroll
            for (int off = 1; off < 16; off <<= 1) sr[r] += __shfl_xor(sr[r], off);
        }
        if (lr == 0) {
#pragma unroll
            for (int r = 0; r < 4; r++)
                atomicAdd(sumsq + b * 256 + o0 + lg * 4 + r, sr[r]);
        }
    }
    if (o0 < 128) {
        float* out = qkvq + (long)b * 524288 + (long)(o0 + lg * 4) * 4096 + n0 + lr;
#pragma unroll
        for (int c = 0; c < 4; c++)
#pragma unroll
            for (int r = 0; r < 4; r++)
                out[r * 4096 + c * 16] = acc[c][r];
    } else if (o0 < 256) {
        // k -> kt[bh][n][32] bf16, transposed via per-wave LDS tile (no barrier:
        // same-wave write->read, compiler inserts lgkmcnt)
        int od0 = o0 - 128;                  // 0..127, multiple of 16
        int h = od0 >> 5;
#pragma unroll
        for (int c = 0; c < 4; c++)
#pragma unroll
            for (int r = 0; r < 4; r++)
                tile[wvid][c * 16 + lr][lg * 4 + r] = f2b(acc[c][r]);
        bf16x8 t0 = *(const bf16x8*)&tile[wvid][lane][0];
        bf16x8 t1 = *(const bf16x8*)&tile[wvid][lane][8];
        u16* dst = kt + ((long)(b * 4 + h)) * 131072 + (long)(n0 + lane) * 32 + (od0 & 16);
        *(bf16x8*)dst = t0;
        *(bf16x8*)(dst + 8) = t1;
    } else {
        u16* out = vb + (long)b * 524288 + (long)(o0 - 256 + lg * 4) * 4096 + n0 + lr;
#pragma unroll
        for (int c = 0; c < 4; c++)
#pragma unroll
            for (int r = 0; r < 4; r++)
                out[r * 4096 + c * 16] = f2b(acc[c][r]);
    }
}

// ---- combined scale for q: 10*log2(e) / (||q_row|| * ||k_row||) ----
__global__ void k_inv(const float* __restrict__ sumsq, float* __restrict__ inv) {
    int i = blockIdx.x * 256 + threadIdx.x;   // 512 rows: [b][128]
    int b = i >> 7, o = i & 127;
    float nq = fmaxf(sqrtf(sumsq[b * 256 + o]), 1e-12f);
    float nk = fmaxf(sqrtf(sumsq[b * 256 + 128 + o]), 1e-12f);
    inv[i] = 14.426950408889634f / (nq * nk);
}

// ---- flash attention, in-register P; block = (bh, 64 i-rows), 8 waves =
// ---- 2 i-subtiles x 4 j-quarters. K/V tiles double-buffered in LDS:
// ---- coalesced global->reg loads issued BEFORE compute, ds_write after
// ---- (T14), fragments via ds_read_b128 (kills L1 address-divergence).
__global__ __launch_bounds__(512, 4) void k_attn(const u16* __restrict__ qt,
                                                 const u16* __restrict__ kt,
                                                 const u16* __restrict__ vb,
                                                 u16* __restrict__ ot) {
    __shared__ __align__(16) u16 ktile[4][2][32][40];  // [js][buf][j][k] pitch 40
    __shared__ __align__(16) u16 vtile[4][2][32][40];  // [js][buf][d][j] pitch 40
    __shared__ f32x4 lacc[3][2][2][2][64];   // [js-1][isub][tau][t][lane]
    __shared__ float lls[3][2][2][64];       // [js-1][isub][tau][lane]
    int wv = threadIdx.x >> 6, lane = threadIdx.x & 63;
    int isub = wv & 1, js = wv >> 1;
    int t = (isub << 6) | lane;              // 0..127 within js-pair
    int bid = blockIdx.x;
    int swz = (bid & 7) * 128 + (bid >> 3);  // XCD swizzle, 1024 % 8 == 0
    int bh = swz >> 6, iblk = swz & 63;
    int lr = lane & 15, lg = lane >> 4;
    long base = (long)bh * 131072;           // 4096*32 elements per (b,h)
    int i0 = iblk * 64 + isub * 32;

    bf16x8 qa[2];
    qa[0] = ldb8(qt + base + (long)(i0 + lr) * 32 + lg * 8);
    qa[1] = ldb8(qt + base + (long)(i0 + 16 + lr) * 32 + lg * 8);

    union { u32 w[4]; bf16x8 v; } ones;
    ones.w[0] = ones.w[1] = ones.w[2] = ones.w[3] = 0x3F803F80u;  // bf16 1.0 x8

    f32x4 z = {0.f, 0.f, 0.f, 0.f};
    f32x4 acc[2][2] = {{z, z}, {z, z}};
    f32x4 accl[2] = {z, z};

    // staging pointers: K tile s = contiguous 2KB; V tile s = 32 rows x 64B
    const u16* Kg = kt + base + (long)js * 32768 + t * 8;
    const u16* Vg = vb + base + (long)(t >> 2) * 4096 + js * 1024 + (t & 3) * 8;
    u16* kw0 = &ktile[js][0][t >> 2][(t & 3) * 8];
    u16* vw0 = &vtile[js][0][t >> 2][(t & 3) * 8];
    u16* kw1 = &ktile[js][1][t >> 2][(t & 3) * 8];
    u16* vw1 = &vtile[js][1][t >> 2][(t & 3) * 8];

    {   // prologue: stage tile 0 into buf 0
        uint4 gk = *(const uint4*)Kg;
        uint4 gv = *(const uint4*)Vg;
        *(uint4*)kw0 = gk;
        *(uint4*)vw0 = gv;
    }
    __syncthreads();

    int cur = 0;
    for (int s = 0; s < 32; s++) {
        uint4 gk, gv;
        if (s < 31) {                        // issue next-tile loads early
            gk = *(const uint4*)(Kg + (s + 1) * 1024);
            gv = *(const uint4*)(Vg + (s + 1) * 32);
        }
        const u16* kb_p = &ktile[js][cur][0][0];
        const u16* vb_p = &vtile[js][cur][0][0];
        bf16x8 kb0 = ldb8(kb_p + lr * 40 + lg * 8);
        bf16x8 kb1 = ldb8(kb_p + (16 + lr) * 40 + lg * 8);
        bf16x8 va0 = ldb8(vb_p + lr * 40 + lg * 8);
        bf16x8 va1 = ldb8(vb_p + (16 + lr) * 40 + lg * 8);
#pragma unroll
        for (int tau = 0; tau < 2; tau++) {
            // Swapped QK^T: lane holds S^T[j = 4*lg + r][i = lr] per 16-j tile.
            f32x4 s0 = MFMA(kb0, qa[tau], z);
            f32x4 s1 = MFMA(kb1, qa[tau], z);
            float p0[4], p1[4];
#pragma unroll
            for (int r = 0; r < 4; r++) {
                p0[r] = __builtin_amdgcn_exp2f(s0[r]);
                p1[r] = __builtin_amdgcn_exp2f(s1[r]);
            }
            // Pack pairs and redistribute: lane lg holds m(2lg),m(2lg+1),
            // m(8+2lg),m(8+2lg+1); B-frag needs m(4lg+e). swap32 then swap16.
            int a0 = cvt_pk(p0[0], p0[1]);
            int a1 = cvt_pk(p0[2], p0[3]);
            int b0 = cvt_pk(p1[0], p1[1]);
            int b1 = cvt_pk(p1[2], p1[3]);
            {
                auto r0_ = __builtin_amdgcn_permlane32_swap(a0, b0, false, false);
                a0 = r0_[0]; b0 = r0_[1];
                auto r1_ = __builtin_amdgcn_permlane32_swap(a1, b1, false, false);
                a1 = r1_[0]; b1 = r1_[1];
                auto r2_ = __builtin_amdgcn_permlane16_swap(a0, b0, false, false);
                a0 = r2_[0]; b0 = r2_[1];
                auto r3_ = __builtin_amdgcn_permlane16_swap(a1, b1, false, false);
                a1 = r3_[0]; b1 = r3_[1];
            }
            union { int w[4]; bf16x8 v; } pu;
            pu.w[0] = a0; pu.w[1] = a1; pu.w[2] = b0; pu.w[3] = b1;
            acc[tau][0] = MFMA(va0, pu.v, acc[tau][0]);
            acc[tau][1] = MFMA(va1, pu.v, acc[tau][1]);
            accl[tau] = MFMA(ones.v, pu.v, accl[tau]);  // row-sums: K-reduce over j
        }
        if (s < 31) {                        // write next buf (vmcnt lands here)
            if (cur) { *(uint4*)kw0 = gk; *(uint4*)vw0 = gv; }
            else     { *(uint4*)kw1 = gk; *(uint4*)vw1 = gv; }
        }
        __syncthreads();
        cur ^= 1;
    }

    if (js > 0) {
#pragma unroll
        for (int tau = 0; tau < 2; tau++) {
            lacc[js - 1][isub][tau][0][lane] = acc[tau][0];
            lacc[js - 1][isub][tau][1][lane] = acc[tau][1];
            lls[js - 1][isub][tau][lane] = accl[tau][0];
        }
    }
    __syncthreads();
    if (js == 0) {
        int b = bh >> 2, h = bh & 3;
#pragma unroll
        for (int tau = 0; tau < 2; tau++) {
            float l = accl[tau][0];
#pragma unroll
            for (int jj = 0; jj < 3; jj++) l += lls[jj][isub][tau][lane];
            float linv = 1.0f / l;
            u16* op = ot + ((long)(b * 4096 + i0 + tau * 16 + lr)) * 128 + h * 32;
#pragma unroll
            for (int t2 = 0; t2 < 2; t2++) {
                f32x4 o = acc[tau][t2];
#pragma unroll
                for (int jj = 0; jj < 3; jj++) o += lacc[jj][isub][tau][t2][lane];
#pragma unroll
                for (int s2 = 0; s2 < 2; s2++) {
                    int w = cvt_pk(o[2 * s2] * linv, o[2 * s2 + 1] * linv);
                    *(int*)(op + 16 * t2 + 4 * lg + 2 * s2) = w;
                }
            }
        }
    }
}

// ---- GEMM2: y[b][256][4096] f32 = Wout(256x128) x O_t + b_out ----
__global__ __launch_bounds__(256) void k_gemm2(const u16* __restrict__ wob,
                                               const u16* __restrict__ ot,
                                               const float* __restrict__ bout,
                                               float* __restrict__ y) {
    int lane = threadIdx.x & 63;
    int wid = blockIdx.x * 4 + (threadIdx.x >> 6);   // 4096 waves
    int b = wid >> 10;
    int rem = wid & 1023;
    int otl = rem >> 6, ng = rem & 63;
    int o0 = otl * 16, n0 = ng * 64;
    int lr = lane & 15, lg = lane >> 4;
    const u16* A = wob + (o0 + lr) * 128 + lg * 8;
    const u16* B = ot + ((long)b * 4096 + n0 + lr) * 128 + lg * 8;
    f32x4 z = {0.f, 0.f, 0.f, 0.f};
    f32x4 acc[4] = {z, z, z, z};
#pragma unroll
    for (int kk = 0; kk < 4; kk++) {
        bf16x8 af = ldb8(A + kk * 32);
#pragma unroll
        for (int c = 0; c < 4; c++) {
            bf16x8 bb = ldb8(B + c * 16 * 128 + kk * 32);
            acc[c] = MFMA(af, bb, acc[c]);
        }
    }
    float bo[4];
#pragma unroll
    for (int r = 0; r < 4; r++) bo[r] = bout[o0 + lg * 4 + r];
    float* out = y + (long)b * 1048576 + (long)(o0 + lg * 4) * 4096 + n0 + lr;
#pragma unroll
    for (int c = 0; c < 4; c++)
#pragma unroll
        for (int r = 0; r < 4; r++)
            out[r * 4096 + c * 16] = acc[c][r] + bo[r];
}

extern "C" void kernel_launch(void* const* d_in, const int* in_sizes, int n_in,
                              void* d_out, int out_size, void* d_ws, size_t ws_size,
                              hipStream_t stream) {
    const float* x    = (const float*)d_in[0];
    const float* wqkv = (const float*)d_in[1];
    const float* wout = (const float*)d_in[2];
    const float* bout = (const float*)d_in[3];
    float* y = (float*)d_out;
    char* ws = (char*)d_ws;

    u16*   wqb   = (u16*)(ws);                 //   196,608 B
    u16*   wob   = (u16*)(ws + 196608);        //    65,536
    u16*   xt    = (u16*)(ws + 262144);        // 8,388,608
    float* qkvq  = (float*)(ws + 8650752);     // 8,388,608  (q only)
    float* inv   = (float*)(ws + 17039360);    //     2,048
    float* sumsq = (float*)(ws + 17041408);    //     4,096
    u16*   qt    = (u16*)(ws + 17045504);      // 4,194,304
    u16*   kt    = (u16*)(ws + 21239808);      // 4,194,304
    u16*   vb    = (u16*)(ws + 25434112);      // 4,194,304
    u16*   ot    = (u16*)(ws + 29628416);      // 4,194,304  -> total 33,822,720 B

    hipMemsetAsync(sumsq, 0, 4096, stream);
    k_convw<<<128, 256, 0, stream>>>(wqkv, wout, wqb, wob);
    k_trans<<<dim3(128, 8, 4), dim3(32, 8), 0, stream>>>(
        x, xt, nullptr, 256, 4096, 1, 1048576L, 0L, 0, 0);
    k_gemm1<<<1536, 256, 0, stream>>>(wqb, xt, qkvq, kt, vb, sumsq);
    k_inv<<<2, 256, 0, stream>>>(sumsq, inv);
    k_trans<<<dim3(128, 1, 16), dim3(32, 8), 0, stream>>>(
        qkvq, qt, inv, 32, 4096, 4, 524288L, 131072L, 128, 32);
    k_attn<<<1024, 512, 0, stream>>>(qt, kt, vb, ot);
    k_gemm2<<<1024, 256, 0, stream>>>(wob, ot, bout, y);
}

// Round 11
// 169.549 us; speedup vs baseline: 1.9794x; 1.1080x over previous
//
#include <hip/hip_runtime.h>
#include <hip/hip_bf16.h>

typedef unsigned short u16;
typedef unsigned int u32;
typedef __attribute__((ext_vector_type(8))) short bf16x8;
typedef __attribute__((ext_vector_type(4))) float f32x4;

#define MFMA(a, b, c) __builtin_amdgcn_mfma_f32_16x16x32_bf16(a, b, c, 0, 0, 0)

__device__ __forceinline__ u16 f2b(float f) {
    u32 x = __float_as_uint(f);
    return (u16)((x + 0x7fffu + ((x >> 16) & 1u)) >> 16);  // RNE, no NaN in data
}
__device__ __forceinline__ bf16x8 ldb8(const u16* p) {
    return *reinterpret_cast<const bf16x8*>(p);
}
__device__ __forceinline__ int cvt_pk(float lo, float hi) {
    int r;
    asm("v_cvt_pk_bf16_f32 %0, %1, %2" : "=v"(r) : "v"(lo), "v"(hi));
    return r;
}

// ---- convert weights to bf16 (w_qkv 384x256, w_out 256x128, same layouts) ----
__global__ void k_convw(const float* wq, const float* wo, u16* wqb, u16* wob) {
    int i4 = (blockIdx.x * 256 + threadIdx.x) * 4;
    const float* s;
    u16* d;
    if (i4 < 384 * 256) { s = wq + i4; d = wqb + i4; }
    else { int j = i4 - 384 * 256; s = wo + j; d = wob + j; }
    float4 v = *(const float4*)s;
    u16 o[4] = {f2b(v.x), f2b(v.y), f2b(v.z), f2b(v.w)};
    *(uint2*)d = *(uint2*)o;
}

// ---- GEMM1 (transpose fused): Wqkv(384x256) x x[b][256][4096].
// ---- Block = (b, 64-n group, ot-half). Stages x^T tile [64n][256c] bf16 in LDS.
// ----   o<128  (q): f32 -> qkvq [b][128][4096] + sumsq atomics
// ----   o<256  (k): sumsq atomics + bf16 kt [bh][4096][32] (LDS repack)
// ----   o>=256 (v): bf16 vb [b][128][4096]
__global__ __launch_bounds__(256) void k_gemm1(const u16* __restrict__ wqb,
                                               const float* __restrict__ x,
                                               float* __restrict__ qkvq,
                                               u16* __restrict__ kt,
                                               u16* __restrict__ vb,
                                               float* __restrict__ sumsq) {
    __shared__ __align__(16) u16 xl[64][264];       // pitch 264: 132 dw -> frag reads 2-way max
    __shared__ __align__(16) u16 tile[4][64][24];   // per-wave kt repack
    int tid = threadIdx.x;
    int lane = tid & 63, wvid = tid >> 6;
    int blk = blockIdx.x;                           // 512 = 4b x 64ng x 2half
    int half = blk & 1, ng = (blk >> 1) & 63, b = blk >> 7;
    int n0 = ng * 64;
    {   // stage x^T: xl[n][c] = bf16(x[b][c][n0+n]); coalesced 256B/row reads
        int ci = tid >> 4, nq = (tid & 15) * 4;
        const float* xb = x + (long)b * 1048576 + n0 + nq;
#pragma unroll
        for (int p = 0; p < 16; p++) {
            int c = ci + p * 16;
            float4 v = *(const float4*)(xb + (long)c * 4096);
            xl[nq + 0][c] = f2b(v.x);
            xl[nq + 1][c] = f2b(v.y);
            xl[nq + 2][c] = f2b(v.z);
            xl[nq + 3][c] = f2b(v.w);
        }
    }
    __syncthreads();
    int lr = lane & 15, lg = lane >> 4;
    f32x4 z = {0.f, 0.f, 0.f, 0.f};
#pragma unroll
    for (int oi = 0; oi < 3; oi++) {
        int ot = half * 12 + wvid * 3 + oi;
        int o0 = ot * 16;
        const u16* A = wqb + (o0 + lr) * 256 + lg * 8;
        f32x4 acc[4] = {z, z, z, z};
#pragma unroll
        for (int kk = 0; kk < 8; kk++) {
            bf16x8 af = ldb8(A + kk * 32);
#pragma unroll
            for (int c4 = 0; c4 < 4; c4++) {
                bf16x8 bb = ldb8(&xl[c4 * 16 + lr][kk * 32 + lg * 8]);
                acc[c4] = MFMA(af, bb, acc[c4]);
            }
        }
        if (o0 < 256) {     // q,k rows: per-row sum of squares
            float sr[4];
#pragma unroll
            for (int r = 0; r < 4; r++) {
                sr[r] = acc[0][r] * acc[0][r] + acc[1][r] * acc[1][r]
                      + acc[2][r] * acc[2][r] + acc[3][r] * acc[3][r];
#pragma unroll
                for (int off = 1; off < 16; off <<= 1) sr[r] += __shfl_xor(sr[r], off);
            }
            if (lr == 0) {
#pragma unroll
                for (int r = 0; r < 4; r++)
                    atomicAdd(sumsq + b * 256 + o0 + lg * 4 + r, sr[r]);
            }
        }
        if (o0 < 128) {
            float* out = qkvq + (long)b * 524288 + (long)(o0 + lg * 4) * 4096 + n0 + lr;
#pragma unroll
            for (int c4 = 0; c4 < 4; c4++)
#pragma unroll
                for (int r = 0; r < 4; r++)
                    out[r * 4096 + c4 * 16] = acc[c4][r];
        } else if (o0 < 256) {
            int od0 = o0 - 128, h = od0 >> 5;
#pragma unroll
            for (int c4 = 0; c4 < 4; c4++)
#pragma unroll
                for (int r = 0; r < 4; r++)
                    tile[wvid][c4 * 16 + lr][lg * 4 + r] = f2b(acc[c4][r]);
            bf16x8 t0 = *(const bf16x8*)&tile[wvid][lane][0];
            bf16x8 t1 = *(const bf16x8*)&tile[wvid][lane][8];
            u16* dst = kt + ((long)(b * 4 + h)) * 131072 + (long)(n0 + lane) * 32 + (od0 & 16);
            *(bf16x8*)dst = t0;
            *(bf16x8*)(dst + 8) = t1;
        } else {
            u16* out = vb + (long)b * 524288 + (long)(o0 - 256 + lg * 4) * 4096 + n0 + lr;
#pragma unroll
            for (int c4 = 0; c4 < 4; c4++)
#pragma unroll
                for (int r = 0; r < 4; r++)
                    out[r * 4096 + c4 * 16] = f2b(acc[c4][r]);
        }
    }
}

// ---- combined scale for q: 10*log2(e) / (||q_row|| * ||k_row||) ----
__global__ void k_inv(const float* __restrict__ sumsq, float* __restrict__ inv) {
    int i = blockIdx.x * 256 + threadIdx.x;   // 512 rows: [b][128]
    int b = i >> 7, o = i & 127;
    float nq = fmaxf(sqrtf(sumsq[b * 256 + o]), 1e-12f);
    float nk = fmaxf(sqrtf(sumsq[b * 256 + 128 + o]), 1e-12f);
    inv[i] = 14.426950408889634f / (nq * nk);
}

// ---- flash attention. Q staged+scaled from f32 in prologue (trans fused).
// ---- K/V tiles double-buffered in FRAG-MAJOR LDS: thread t writes slot t
// ---- (linear, conflict-free), global source pre-permuted so slot L == lane
// ---- L's MFMA fragment (conflict-free ds_read_b128). Partials overlay tiles
// ---- via union -> 36.9KB LDS -> 4 blocks/CU, 8 waves/SIMD.
__global__ __launch_bounds__(512, 8) void k_attn(const float* __restrict__ qkvq,
                                                 const float* __restrict__ inv,
                                                 const u16* __restrict__ kt,
                                                 const u16* __restrict__ vb,
                                                 u16* __restrict__ ot) {
    union SmemU {
        struct { u16 k[4][2][2][64][8]; u16 v[4][2][2][64][8]; } t;  // 32768 B
        struct { f32x4 lacc[3][2][2][2][64]; float lls[3][2][2][64]; } p;  // 30720 B
    };
    __shared__ __align__(16) SmemU sm;
    __shared__ __align__(16) u16 qtF[2][2][64][8];  // 4096 B

    int wv = threadIdx.x >> 6, lane = threadIdx.x & 63;
    int isub = wv & 1, js = wv >> 1;
    int t = (isub << 6) | lane;              // 0..127 within js-pair
    int bid = blockIdx.x;
    int swz = (bid & 7) * 128 + (bid >> 3);  // XCD swizzle, 1024 % 8 == 0
    int bh = swz >> 6, iblk = swz & 63;
    int lr = lane & 15, lg = lane >> 4;
    int b = bh >> 2, head = bh & 3;
    long base = (long)bh * 131072;
    int i0g = iblk * 64;
    int i0 = i0g + isub * 32;

    // ---- stage Q (scaled by inv) into frag-major LDS ----
    {
        int u = threadIdx.x;
        int d = u >> 4, iq = (u & 15) * 4;
        const float* qsrc = qkvq + (long)b * 524288 + (long)(head * 32 + d) * 4096 + i0g + iq;
        float sc = inv[b * 128 + head * 32 + d];
        float4 v4 = *(const float4*)qsrc;
        float vv[4] = {v4.x, v4.y, v4.z, v4.w};
        int lg2 = d >> 3, e = d & 7;
#pragma unroll
        for (int q = 0; q < 4; q++) {
            int i = iq + q;
            qtF[i >> 5][(i >> 4) & 1][lg2 * 16 + (i & 15)][e] = f2b(vv[q] * sc);
        }
    }

    // pre-permuted global sources: thread t loads the chunk that belongs at
    // LDS slot t. Slot (f=t>>6, L=t&63): kb frag f, lane L = K row f*16+(L&15),
    // cols ((L>>4)&3)*8; va frag f: V d-row f*16+(L&15), j-cols ((L>>4)&3)*8.
    int kperm = (t >> 6) * 512 + (t & 15) * 32 + ((t >> 4) & 3) * 8;
    int vperm = ((t >> 6) * 16 + (t & 15)) * 4096 + ((t >> 4) & 3) * 8;
    const u16* Kg = kt + base + js * 32768 + kperm;
    const u16* Vg = vb + base + js * 1024 + vperm;
    u16* kws = &sm.t.k[js][0][t >> 6][t & 63][0];   // buf1 = +1024 u16
    u16* vws = &sm.t.v[js][0][t >> 6][t & 63][0];

    union { u32 w[4]; bf16x8 v8; } ones;
    ones.w[0] = ones.w[1] = ones.w[2] = ones.w[3] = 0x3F803F80u;  // bf16 1.0 x8

    f32x4 z = {0.f, 0.f, 0.f, 0.f};
    f32x4 acc[2][2] = {{z, z}, {z, z}};
    f32x4 accl[2] = {z, z};

    {   // prologue: stage tile 0 into buf 0 (also covers Q-stage barrier)
        uint4 gk = *(const uint4*)Kg;
        uint4 gv = *(const uint4*)Vg;
        *(uint4*)kws = gk;
        *(uint4*)vws = gv;
    }
    __syncthreads();
    bf16x8 qa[2];
    qa[0] = ldb8(&qtF[isub][0][lane][0]);
    qa[1] = ldb8(&qtF[isub][1][lane][0]);

    int cur = 0;
    for (int s = 0; s < 32; s++) {
        uint4 gk, gv;
        if (s < 31) {                        // issue next-tile loads early
            gk = *(const uint4*)(Kg + (s + 1) * 1024);
            gv = *(const uint4*)(Vg + (s + 1) * 32);
        }
        bf16x8 kb0 = ldb8(&sm.t.k[js][cur][0][lane][0]);
        bf16x8 kb1 = ldb8(&sm.t.k[js][cur][1][lane][0]);
        bf16x8 va0 = ldb8(&sm.t.v[js][cur][0][lane][0]);
        bf16x8 va1 = ldb8(&sm.t.v[js][cur][1][lane][0]);
#pragma unroll
        for (int tau = 0; tau < 2; tau++) {
            // Swapped QK^T: lane holds S^T[j = 4*lg + r][i = lr] per 16-j tile.
            f32x4 s0 = MFMA(kb0, qa[tau], z);
            f32x4 s1 = MFMA(kb1, qa[tau], z);
            float p0[4], p1[4];
#pragma unroll
            for (int r = 0; r < 4; r++) {
                p0[r] = __builtin_amdgcn_exp2f(s0[r]);
                p1[r] = __builtin_amdgcn_exp2f(s1[r]);
            }
            // Pack pairs and redistribute: lane lg holds m(2lg),m(2lg+1),
            // m(8+2lg),m(8+2lg+1); B-frag needs m(4lg+e). swap32 then swap16.
            int a0 = cvt_pk(p0[0], p0[1]);
            int a1 = cvt_pk(p0[2], p0[3]);
            int b0 = cvt_pk(p1[0], p1[1]);
            int b1 = cvt_pk(p1[2], p1[3]);
            {
                auto r0_ = __builtin_amdgcn_permlane32_swap(a0, b0, false, false);
                a0 = r0_[0]; b0 = r0_[1];
                auto r1_ = __builtin_amdgcn_permlane32_swap(a1, b1, false, false);
                a1 = r1_[0]; b1 = r1_[1];
                auto r2_ = __builtin_amdgcn_permlane16_swap(a0, b0, false, false);
                a0 = r2_[0]; b0 = r2_[1];
                auto r3_ = __builtin_amdgcn_permlane16_swap(a1, b1, false, false);
                a1 = r3_[0]; b1 = r3_[1];
            }
            union { int w[4]; bf16x8 v; } pu;
            pu.w[0] = a0; pu.w[1] = a1; pu.w[2] = b0; pu.w[3] = b1;
            acc[tau][0] = MFMA(va0, pu.v, acc[tau][0]);
            acc[tau][1] = MFMA(va1, pu.v, acc[tau][1]);
            accl[tau] = MFMA(ones.v8, pu.v, accl[tau]);  // row-sums over j
        }
        if (s < 31) {                        // write next buf (vmcnt lands here)
            *(uint4*)(kws + ((cur ^ 1) << 10)) = gk;
            *(uint4*)(vws + ((cur ^ 1) << 10)) = gv;
        }
        __syncthreads();
        cur ^= 1;
    }

    // partial combine: overlay tiles region (barrier above separates uses)
    if (js > 0) {
#pragma unroll
        for (int tau = 0; tau < 2; tau++) {
            sm.p.lacc[js - 1][isub][tau][0][lane] = acc[tau][0];
            sm.p.lacc[js - 1][isub][tau][1][lane] = acc[tau][1];
            sm.p.lls[js - 1][isub][tau][lane] = accl[tau][0];
        }
    }
    __syncthreads();
    if (js == 0) {
#pragma unroll
        for (int tau = 0; tau < 2; tau++) {
            float l = accl[tau][0];
#pragma unroll
            for (int jj = 0; jj < 3; jj++) l += sm.p.lls[jj][isub][tau][lane];
            float linv = 1.0f / l;
            u16* op = ot + ((long)(b * 4096 + i0 + tau * 16 + lr)) * 128 + head * 32;
#pragma unroll
            for (int t2 = 0; t2 < 2; t2++) {
                f32x4 o = acc[tau][t2];
#pragma unroll
                for (int jj = 0; jj < 3; jj++) o += sm.p.lacc[jj][isub][tau][t2][lane];
#pragma unroll
                for (int s2 = 0; s2 < 2; s2++) {
                    int w = cvt_pk(o[2 * s2] * linv, o[2 * s2 + 1] * linv);
                    *(int*)(op + 16 * t2 + 4 * lg + 2 * s2) = w;
                }
            }
        }
    }
}

// ---- GEMM2: y[b][256][4096] f32 = Wout(256x128) x O_t + b_out ----
__global__ __launch_bounds__(256) void k_gemm2(const u16* __restrict__ wob,
                                               const u16* __restrict__ ot,
                                               const float* __restrict__ bout,
                                               float* __restrict__ y) {
    int lane = threadIdx.x & 63;
    int wid = blockIdx.x * 4 + (threadIdx.x >> 6);   // 4096 waves
    int b = wid >> 10;
    int rem = wid & 1023;
    int otl = rem >> 6, ng = rem & 63;
    int o0 = otl * 16, n0 = ng * 64;
    int lr = lane & 15, lg = lane >> 4;
    const u16* A = wob + (o0 + lr) * 128 + lg * 8;
    const u16* B = ot + ((long)b * 4096 + n0 + lr) * 128 + lg * 8;
    f32x4 z = {0.f, 0.f, 0.f, 0.f};
    f32x4 acc[4] = {z, z, z, z};
#pragma unroll
    for (int kk = 0; kk < 4; kk++) {
        bf16x8 af = ldb8(A + kk * 32);
#pragma unroll
        for (int c = 0; c < 4; c++) {
            bf16x8 bb = ldb8(B + c * 16 * 128 + kk * 32);
            acc[c] = MFMA(af, bb, acc[c]);
        }
    }
    float bo[4];
#pragma unroll
    for (int r = 0; r < 4; r++) bo[r] = bout[o0 + lg * 4 + r];
    float* out = y + (long)b * 1048576 + (long)(o0 + lg * 4) * 4096 + n0 + lr;
#pragma unroll
    for (int c = 0; c < 4; c++)
#pragma unroll
        for (int r = 0; r < 4; r++)
            out[r * 4096 + c * 16] = acc[c][r] + bo[r];
}

extern "C" void kernel_launch(void* const* d_in, const int* in_sizes, int n_in,
                              void* d_out, int out_size, void* d_ws, size_t ws_size,
                              hipStream_t stream) {
    const float* x    = (const float*)d_in[0];
    const float* wqkv = (const float*)d_in[1];
    const float* wout = (const float*)d_in[2];
    const float* bout = (const float*)d_in[3];
    float* y = (float*)d_out;
    char* ws = (char*)d_ws;

    u16*   wqb   = (u16*)(ws);                 //   196,608 B
    u16*   wob   = (u16*)(ws + 196608);        //    65,536
    float* qkvq  = (float*)(ws + 262144);      // 8,388,608  (q only, f32)
    float* inv   = (float*)(ws + 8650752);     //     2,048
    float* sumsq = (float*)(ws + 8652800);     //     4,096
    u16*   kt    = (u16*)(ws + 8656896);       // 4,194,304
    u16*   vb    = (u16*)(ws + 12851200);      // 4,194,304
    u16*   ot    = (u16*)(ws + 17045504);      // 4,194,304  -> total 21,239,808 B

    hipMemsetAsync(sumsq, 0, 4096, stream);
    k_convw<<<128, 256, 0, stream>>>(wqkv, wout, wqb, wob);
    k_gemm1<<<512, 256, 0, stream>>>(wqb, x, qkvq, kt, vb, sumsq);
    k_inv<<<2, 256, 0, stream>>>(sumsq, inv);
    k_attn<<<1024, 512, 0, stream>>>(qkvq, inv, kt, vb, ot);
    k_gemm2<<<1024, 256, 0, stream>>>(wob, ot, bout, y);
}